// Round 7
// baseline (574.969 us; speedup 1.0000x reference)
//
#include <hip/hip_runtime.h>

#define NPTS 250000

typedef float4 f4;

// ---------------------------------------------------------------------------
// Three barrier-free kernels, all targeting <=64 VGPR (8 waves/SIMD) so
// memory latency is hidden by TLP. R6 counters showed: weight arrays in
// VGPRs either spill (k2: VGPR=56, 148MB scratch writes) or cap occupancy
// (k1: VGPR=124, 17.7% occ). Fix: k0 owns the w10 GEMM; k1/k2 keep only the
// center-offset weights in regs and let them die before the event loop;
// no LDS, no __syncthreads anywhere.
// block = 256 thr = 4 waves; each wave owns 4 points. Lane -> (c = lane&31
// output channel, kh = lane>>5 k-half). 250000 = 15625 blocks * 16 points.
// ---------------------------------------------------------------------------

// k0: t = relu(feats @ w10)   [N,64] @ [64,32]
__global__ __launch_bounds__(256) void k0(
    const float* __restrict__ feats, const float* __restrict__ w10,
    float* __restrict__ t_out)
{
    const int tid = threadIdx.x, lane = tid & 63;
    const int wv = tid >> 6, c = lane & 31, kh = lane >> 5;
    const int i0 = blockIdx.x * 16 + wv * 4;

    float wB[32];
    #pragma unroll
    for (int kk = 0; kk < 32; ++kk)
        wB[kk] = w10[(size_t)(kh * 32 + kk) * 32 + c];

    #pragma unroll
    for (int p = 0; p < 4; ++p) {
        const f4* __restrict__ xr =
            reinterpret_cast<const f4*>(feats + (size_t)(i0 + p) * 64 + kh * 32);
        float a = 0.f;
        #pragma unroll
        for (int q = 0; q < 8; ++q) {
            const f4 x = xr[q];
            a = fmaf(x.x, wB[4*q+0], a);
            a = fmaf(x.y, wB[4*q+1], a);
            a = fmaf(x.z, wB[4*q+2], a);
            a = fmaf(x.w, wB[4*q+3], a);
        }
        a += __shfl_xor(a, 32);
        if (kh == 0) t_out[(size_t)(i0 + p) * 32 + c] = fmaxf(a, 0.f);
    }
}

// ---- k1: h0 = relu(conv3(feats, w00)) ------------------------------------

__device__ __forceinline__ void k1_event(int f, int j, int kh, int c,
    const float* __restrict__ feats, const float* __restrict__ w00,
    float& a00, float& a01, float& a02, float& a03)
{
    const int p = f / 27, o = f % 27;
    const f4* __restrict__ xr = reinterpret_cast<const f4*>(feats + (size_t)j * 64 + kh * 32);
    const float* __restrict__ w = w00 + (size_t)(o * 64 + kh * 32) * 32 + c;
    float a = 0.f;
    #pragma unroll
    for (int q = 0; q < 8; ++q) {
        const f4 x = xr[q];
        a = fmaf(x.x, w[(4*q+0)*32], a);
        a = fmaf(x.y, w[(4*q+1)*32], a);
        a = fmaf(x.z, w[(4*q+2)*32], a);
        a = fmaf(x.w, w[(4*q+3)*32], a);
    }
    if      (p == 0) a00 += a;
    else if (p == 1) a01 += a;
    else if (p == 2) a02 += a;
    else             a03 += a;
}

__global__ __launch_bounds__(256) void k1(
    const float* __restrict__ feats, const float* __restrict__ w00,
    const int* __restrict__ nbr, float* __restrict__ h0)
{
    const int tid = threadIdx.x, lane = tid & 63;
    const int wv = tid >> 6, c = lane & 31, kh = lane >> 5;
    const int i0 = blockIdx.x * 16 + wv * 4;

    // issue the long-latency nbr load first; center compute hides it
    int2 nv = make_int2(-1, -1);
    if (lane < 54) nv = reinterpret_cast<const int2*>(nbr + (size_t)i0 * 27)[lane];

    // center weights only (L2-warm broadcast); dead after the center phase
    float wA[32];
    #pragma unroll
    for (int kk = 0; kk < 32; ++kk)
        wA[kk] = w00[(size_t)(13 * 64 + kh * 32 + kk) * 32 + c];

    float a00 = 0, a01 = 0, a02 = 0, a03 = 0;
    #pragma unroll
    for (int p = 0; p < 4; ++p) {
        const f4* __restrict__ xr =
            reinterpret_cast<const f4*>(feats + (size_t)(i0 + p) * 64 + kh * 32);
        float a = 0.f;
        #pragma unroll
        for (int q = 0; q < 8; ++q) {
            const f4 x = xr[q];
            a = fmaf(x.x, wA[4*q+0], a);
            a = fmaf(x.y, wA[4*q+1], a);
            a = fmaf(x.z, wA[4*q+2], a);
            a = fmaf(x.w, wA[4*q+3], a);
        }
        if      (p == 0) a00 = a;
        else if (p == 1) a01 = a;
        else if (p == 2) a02 = a;
        else             a03 = a;
    }

    // sparse events: flat f = 2*lane+e in [0,108) -> point f/27, offset f%27
    unsigned long long b0 = __ballot(lane < 54 && nv.x >= 0 && ((2 * lane    ) % 27) != 13);
    unsigned long long b1 = __ballot(lane < 54 && nv.y >= 0 && ((2 * lane + 1) % 27) != 13);
    while (b0) {
        const int L = __builtin_ctzll(b0); b0 &= b0 - 1;
        const int j = __shfl(nv.x, L);
        k1_event(2 * L, j, kh, c, feats, w00, a00, a01, a02, a03);
    }
    while (b1) {
        const int L = __builtin_ctzll(b1); b1 &= b1 - 1;
        const int j = __shfl(nv.y, L);
        k1_event(2 * L + 1, j, kh, c, feats, w00, a00, a01, a02, a03);
    }

    #pragma unroll
    for (int p = 0; p < 4; ++p) {
        float a0 = (p == 0) ? a00 : (p == 1) ? a01 : (p == 2) ? a02 : a03;
        a0 += __shfl_xor(a0, 32);
        if (kh == 0) h0[(size_t)(i0 + p) * 32 + c] = fmaxf(a0, 0.f);
    }
}

// ---- k2: out = concat(conv3(h0,w01), relu(conv3(t,w11))@w12) + feats -----

__device__ __forceinline__ void k2_event(int f, int j, int kh, int c,
    const float* __restrict__ h0, const float* __restrict__ t_in,
    const float* __restrict__ w01, const float* __restrict__ w11,
    float& a00, float& a01, float& a02, float& a03,
    float& a10, float& a11, float& a12, float& a13)
{
    const int p = f / 27, o = f % 27;
    const f4* __restrict__ hr = reinterpret_cast<const f4*>(h0   + (size_t)j * 32 + kh * 16);
    const f4* __restrict__ tr = reinterpret_cast<const f4*>(t_in + (size_t)j * 32 + kh * 16);
    const float* __restrict__ wa = w01 + (size_t)(o * 32 + kh * 16) * 32 + c;
    const float* __restrict__ wb = w11 + (size_t)(o * 32 + kh * 16) * 32 + c;
    float a = 0.f, b = 0.f;
    #pragma unroll
    for (int q = 0; q < 4; ++q) {
        const f4 h = hr[q];
        a = fmaf(h.x, wa[(4*q+0)*32], a);
        a = fmaf(h.y, wa[(4*q+1)*32], a);
        a = fmaf(h.z, wa[(4*q+2)*32], a);
        a = fmaf(h.w, wa[(4*q+3)*32], a);
        const f4 u = tr[q];
        b = fmaf(u.x, wb[(4*q+0)*32], b);
        b = fmaf(u.y, wb[(4*q+1)*32], b);
        b = fmaf(u.z, wb[(4*q+2)*32], b);
        b = fmaf(u.w, wb[(4*q+3)*32], b);
    }
    if      (p == 0) { a00 += a; a10 += b; }
    else if (p == 1) { a01 += a; a11 += b; }
    else if (p == 2) { a02 += a; a12 += b; }
    else             { a03 += a; a13 += b; }
}

__global__ __launch_bounds__(256) void k2(
    const float* __restrict__ h0, const float* __restrict__ t_in,
    const float* __restrict__ w01, const float* __restrict__ w11,
    const float* __restrict__ w12, const float* __restrict__ feats,
    const int* __restrict__ nbr, float* __restrict__ out)
{
    const int tid = threadIdx.x, lane = tid & 63;
    const int wv = tid >> 6, c = lane & 31, kh = lane >> 5;
    const int i0 = blockIdx.x * 16 + wv * 4;

    int2 nv = make_int2(-1, -1);
    if (lane < 54) nv = reinterpret_cast<const int2*>(nbr + (size_t)i0 * 27)[lane];

    // center weights for both conv paths; dead after center phase
    float wA[16], wB[16];
    #pragma unroll
    for (int kk = 0; kk < 16; ++kk) {
        const int k = kh * 16 + kk;
        wA[kk] = w01[(size_t)(13 * 32 + k) * 32 + c];
        wB[kk] = w11[(size_t)(13 * 32 + k) * 32 + c];
    }

    float a00 = 0, a01 = 0, a02 = 0, a03 = 0;
    float a10 = 0, a11 = 0, a12 = 0, a13 = 0;
    #pragma unroll
    for (int p = 0; p < 4; ++p) {
        const f4* __restrict__ hr =
            reinterpret_cast<const f4*>(h0   + (size_t)(i0 + p) * 32 + kh * 16);
        const f4* __restrict__ tr =
            reinterpret_cast<const f4*>(t_in + (size_t)(i0 + p) * 32 + kh * 16);
        float a0 = 0.f, a1 = 0.f;
        #pragma unroll
        for (int q = 0; q < 4; ++q) {
            const f4 h = hr[q];
            a0 = fmaf(h.x, wA[4*q+0], a0);
            a0 = fmaf(h.y, wA[4*q+1], a0);
            a0 = fmaf(h.z, wA[4*q+2], a0);
            a0 = fmaf(h.w, wA[4*q+3], a0);
            const f4 u = tr[q];
            a1 = fmaf(u.x, wB[4*q+0], a1);
            a1 = fmaf(u.y, wB[4*q+1], a1);
            a1 = fmaf(u.z, wB[4*q+2], a1);
            a1 = fmaf(u.w, wB[4*q+3], a1);
        }
        if      (p == 0) { a00 = a0; a10 = a1; }
        else if (p == 1) { a01 = a0; a11 = a1; }
        else if (p == 2) { a02 = a0; a12 = a1; }
        else             { a03 = a0; a13 = a1; }
    }

    unsigned long long b0 = __ballot(lane < 54 && nv.x >= 0 && ((2 * lane    ) % 27) != 13);
    unsigned long long b1 = __ballot(lane < 54 && nv.y >= 0 && ((2 * lane + 1) % 27) != 13);
    while (b0) {
        const int L = __builtin_ctzll(b0); b0 &= b0 - 1;
        const int j = __shfl(nv.x, L);
        k2_event(2 * L, j, kh, c, h0, t_in, w01, w11, a00, a01, a02, a03, a10, a11, a12, a13);
    }
    while (b1) {
        const int L = __builtin_ctzll(b1); b1 &= b1 - 1;
        const int j = __shfl(nv.y, L);
        k2_event(2 * L + 1, j, kh, c, h0, t_in, w01, w11, a00, a01, a02, a03, a10, a11, a12, a13);
    }

    // finalize: wC loaded only now (L2-warm); t2 @ w12 via shfl broadcasts
    float wC[16];
    #pragma unroll
    for (int kk = 0; kk < 16; ++kk)
        wC[kk] = w12[(size_t)(kh * 16 + kk) * 32 + c];

    #pragma unroll
    for (int p = 0; p < 4; ++p) {
        float a0 = (p == 0) ? a00 : (p == 1) ? a01 : (p == 2) ? a02 : a03;
        float a1 = (p == 0) ? a10 : (p == 1) ? a11 : (p == 2) ? a12 : a13;
        a0 += __shfl_xor(a0, 32);
        a1 += __shfl_xor(a1, 32);
        const float t2 = fmaxf(a1, 0.f);   // full value for channel c
        float o1 = 0.f;
        #pragma unroll
        for (int kk = 0; kk < 16; ++kk) {
            const float tk = __shfl(t2, kh * 16 + kk);   // channel kh*16+kk
            o1 = fmaf(tk, wC[kk], o1);
        }
        o1 += __shfl_xor(o1, 32);
        const int i = i0 + p;
        const float res = feats[(size_t)i * 64 + kh * 32 + c];
        out[(size_t)i * 64 + kh * 32 + c] = (kh == 0 ? a0 : o1) + res;
    }
}

extern "C" void kernel_launch(void* const* d_in, const int* in_sizes, int n_in,
                              void* d_out, int out_size, void* d_ws, size_t ws_size,
                              hipStream_t stream)
{
    const float* feats = (const float*)d_in[0];
    const float* w00   = (const float*)d_in[1];
    const float* w01   = (const float*)d_in[2];
    const float* w10   = (const float*)d_in[3];
    const float* w11   = (const float*)d_in[4];
    const float* w12   = (const float*)d_in[5];
    const int*   nbr   = (const int*)d_in[6];
    float* out = (float*)d_out;

    float* h0 = (float*)d_ws;                  // [N,32] f32
    float* t  = h0 + (size_t)NPTS * 32;        // [N,32] f32

    const int blocks = NPTS / 16;              // 15625, exact
    k0<<<blocks, 256, 0, stream>>>(feats, w10, t);
    k1<<<blocks, 256, 0, stream>>>(feats, w00, nbr, h0);
    k2<<<blocks, 256, 0, stream>>>(h0, t, w01, w11, w12, feats, nbr, out);
}